// Round 2
// baseline (141.325 us; speedup 1.0000x reference)
//
#include <hip/hip_runtime.h>
#include <stdint.h>

#define M_DIM 16384
#define N_DIM 1024
#define K_DIM 1024

#define BM 128
#define BN 128
#define BK 64

using i32x4 = __attribute__((ext_vector_type(4))) int;

__device__ __forceinline__ int pack4(int4 v) {
    return (v.x & 0xFF) | ((v.y & 0xFF) << 8) | ((v.z & 0xFF) << 16) | ((v.w & 0xFF) << 24);
}

// ---------------- pack x: int32 [M,K] -> int8 [M,K] ----------------
__global__ __launch_bounds__(256) void pack_x_kernel(const int* __restrict__ x,
                                                     int8_t* __restrict__ xq) {
    const int4* xin = (const int4*)x;
    int* xout = (int*)xq;
    size_t base = (size_t)blockIdx.x * 1024;  // int4 units per block
    int tid = threadIdx.x;
#pragma unroll
    for (int i = 0; i < 4; ++i) {
        size_t idx = base + (size_t)i * 256 + tid;
        int4 v = xin[idx];          // 16B coalesced load (4 int32 elems)
        xout[idx] = pack4(v);       // 4B coalesced store (4 int8 elems)
    }
}

// ------------- pack w + corr: one block per output column ----------
// corr[n] = bias[n] - 3 * sum_k w[n,k]
__global__ __launch_bounds__(256) void pack_w_corr_kernel(const int* __restrict__ w,
                                                          const int* __restrict__ bias,
                                                          int8_t* __restrict__ wq,
                                                          int* __restrict__ corr) {
    int col = blockIdx.x;
    int t = threadIdx.x;
    int4 v = ((const int4*)(w + (size_t)col * K_DIM))[t];  // 4 elems
    ((int*)(wq + (size_t)col * K_DIM))[t] = pack4(v);
    int s = v.x + v.y + v.z + v.w;
#pragma unroll
    for (int m = 1; m < 64; m <<= 1) s += __shfl_xor(s, m);
    __shared__ int partial[4];
    if ((t & 63) == 0) partial[t >> 6] = s;
    __syncthreads();
    if (t == 0) {
        int total = partial[0] + partial[1] + partial[2] + partial[3];
        corr[col] = bias[col] - 3 * total;
    }
}

// ---------------- GEMM: C = Xq (i8) * Wq^T (i8) + corr, requant ----------------
// 128x128 tile, BK=64, 4 waves (2x2 of 64x64 each), mfma_i32_16x16x64_i8.
__global__ __launch_bounds__(256) void gemm_kernel(const int8_t* __restrict__ A,
                                                   const int8_t* __restrict__ B,
                                                   const int* __restrict__ corr,
                                                   int* __restrict__ out) {
    __shared__ int8_t Asm[BM * BK];  // [128][64] linear, row-major
    __shared__ int8_t Bsm[BN * BK];

    int bid = blockIdx.x;
    // XCD-bijective swizzle: nwg = 1024 divisible by 8. XCD x owns 16
    // contiguous m-panels (2MB A i8) + full B (1MB) -> fits 4MB L2.
    int swz = (bid & 7) * 128 + (bid >> 3);
    int mtile = swz >> 3;   // 0..127
    int ntile = swz & 7;    // 0..7
    int m0 = mtile * BM;
    int n0 = ntile * BN;

    int tid = threadIdx.x;
    int lane = tid & 63;
    int wave = tid >> 6;
    int wm = wave >> 1;     // 0..1
    int wn = wave & 1;      // 0..1

    i32x4 acc[4][4];
#pragma unroll
    for (int i = 0; i < 4; ++i)
#pragma unroll
        for (int j = 0; j < 4; ++j)
            acc[i][j] = (i32x4){0, 0, 0, 0};

    int r16 = lane & 15;
    int krow = lane >> 4;   // 0..3  -> k-offset krow*16

    for (int kt = 0; kt < K_DIM / BK; ++kt) {
        const int8_t* Ag = A + (size_t)m0 * K_DIM + kt * BK;
        const int8_t* Bg = B + (size_t)n0 * K_DIM + kt * BK;
        // Stage: 8KB per tile = 2 iters x 256 threads x 16B, linear LDS dest
        // (wave-uniform base + lane*16, as global_load_lds requires).
#pragma unroll
        for (int i = 0; i < 2; ++i) {
            int f = i * 256 + tid;
            int row = f >> 2, ch = f & 3;
            __builtin_amdgcn_global_load_lds(
                (const __attribute__((address_space(1))) unsigned int*)(Ag + (size_t)row * K_DIM + ch * 16),
                (__attribute__((address_space(3))) unsigned int*)(Asm + f * 16),
                16, 0, 0);
        }
#pragma unroll
        for (int i = 0; i < 2; ++i) {
            int f = i * 256 + tid;
            int row = f >> 2, ch = f & 3;
            __builtin_amdgcn_global_load_lds(
                (const __attribute__((address_space(1))) unsigned int*)(Bg + (size_t)row * K_DIM + ch * 16),
                (__attribute__((address_space(3))) unsigned int*)(Bsm + f * 16),
                16, 0, 0);
        }
        __syncthreads();

        // Fragments: A lane -> row = lane&15 (+16*i), k = (lane>>4)*16 + [0..15]
        i32x4 afr[4], bfr[4];
#pragma unroll
        for (int i = 0; i < 4; ++i) {
            afr[i] = *(const i32x4*)(Asm + (wm * 64 + i * 16 + r16) * BK + krow * 16);
            bfr[i] = *(const i32x4*)(Bsm + (wn * 64 + i * 16 + r16) * BK + krow * 16);
        }
#pragma unroll
        for (int i = 0; i < 4; ++i)
#pragma unroll
            for (int j = 0; j < 4; ++j)
                acc[i][j] = __builtin_amdgcn_mfma_i32_16x16x64_i8(afr[i], bfr[j], acc[i][j], 0, 0, 0);
        __syncthreads();
    }

    // Epilogue: C/D layout col = lane&15, row = (lane>>4)*4 + reg.
    int col16 = lane & 15;
    int rbase = (lane >> 4) * 4;
#pragma unroll
    for (int j = 0; j < 4; ++j) {
        int c = n0 + wn * 64 + j * 16 + col16;
        int cr = corr[c];
#pragma unroll
        for (int i = 0; i < 4; ++i) {
            int rrow = m0 + wm * 64 + i * 16 + rbase;
#pragma unroll
            for (int r = 0; r < 4; ++r) {
                int t = acc[i][j][r] + cr;
                int res = ((t * 10) >> 10) - 5;       // floor((acc*10)/1024) + OUTPUT_ZP
                res = res < -128 ? -128 : (res > 127 ? 127 : res);
                out[(size_t)(rrow + r) * N_DIM + c] = res;   // int32 store
            }
        }
    }
}

extern "C" void kernel_launch(void* const* d_in, const int* in_sizes, int n_in,
                              void* d_out, int out_size, void* d_ws, size_t ws_size,
                              hipStream_t stream) {
    (void)in_sizes; (void)n_in; (void)out_size; (void)ws_size;
    const int* x    = (const int*)d_in[0];
    const int* w    = (const int*)d_in[1];
    const int* bias = (const int*)d_in[2];
    int* out = (int*)d_out;

    int8_t* xq = (int8_t*)d_ws;                          // 16 MiB
    int8_t* wq = xq + (size_t)M_DIM * K_DIM;             // 1 MiB
    int* corr  = (int*)(wq + (size_t)N_DIM * K_DIM);     // 4 KiB

    pack_x_kernel<<<4096, 256, 0, stream>>>(x, xq);
    pack_w_corr_kernel<<<N_DIM, 256, 0, stream>>>(w, bias, wq, corr);
    gemm_kernel<<<(M_DIM / BM) * (N_DIM / BN), 256, 0, stream>>>(xq, wq, corr, out);
}